// Round 5
// baseline (1838.566 us; speedup 1.0000x reference)
//
#include <hip/hip_runtime.h>

// GNNModel fused via fp16 MFMA 16x16x32. Adjacency bit-exact fp32.
// R5: persistent-ish blocks (grid 2048, 8 groups of NB=4 batches each),
// register prefetch of next group's x, shfl-based adjacency, LDS 37.5 KB
// -> 4 blocks/CU. Evidence (R3 vs R4): barriers cheap, latency dominant.

typedef _Float16 half8v  __attribute__((ext_vector_type(8)));
typedef _Float16 half4v  __attribute__((ext_vector_type(4)));
typedef float    float4v __attribute__((ext_vector_type(4)));

constexpr int PP = 12, DIN = 32, H = 128, HO = 64, DOUT = 3, NL = 3;
constexpr int NB = 4, ROWS = NB * PP;   // 48 rows per group
constexpr int HP  = 136;                // h_a stride (halves): 272B -> 4-bank rotation
constexpr int TP  = 72;                 // tT stride: 144B; K padded 48->64
constexpr int AP2 = 72;                 // AmatT stride
constexpr int GRID = 2048;              // blocks; ngroups = B/(GRID*NB) = 8

// ws layout in halves: WinT[128][32] @0 ; WgT[3][128][128] @4096 ; W1T[64][128] @53248
constexpr int WS_WG = 4096, WS_W1 = 53248, WS_TOT = 61440;

__global__ __launch_bounds__(256)
void prep_weights(const float* __restrict__ W_in, const float* __restrict__ W_gcn,
                  const float* __restrict__ W_out1, _Float16* __restrict__ ws)
{
    int e = blockIdx.x * 256 + threadIdx.x;
    if (e < WS_WG) {                        // WinT[n][k] = W_in[k][n]
        int n = e >> 5, k = e & 31;
        ws[e] = (_Float16)W_in[k * H + n];
    } else if (e < WS_W1) {                 // WgT[l][n][k] = W_gcn[l][k][n]
        int e2 = e - WS_WG;
        int l = e2 >> 14, r = e2 & 16383, n = r >> 7, k = r & 127;
        ws[e] = (_Float16)W_gcn[l * (H * H) + k * H + n];
    } else if (e < WS_TOT) {                // W1T[o][k] = W_out1[k][o]
        int e3 = e - WS_W1;
        int o = e3 >> 7, k = e3 & 127;
        ws[e] = (_Float16)W_out1[k * HO + o];
    }
}

__global__ __launch_bounds__(256, 4)
void gnn_mfma(const float* __restrict__ x,
              const float* __restrict__ b_in,
              const float* __restrict__ b_gcn,
              const float* __restrict__ b_out1,
              const float* __restrict__ W_out2,
              const float* __restrict__ b_out2,
              const _Float16* __restrict__ ws,
              float* __restrict__ out,
              int ngroups)
{
    __shared__ _Float16 h_a[ROWS][HP];                 // 12.75 KB
    __shared__ _Float16 tT[H][TP];                     // 18 KB (wave-private rows)
    __shared__ __align__(16) char r3[ROWS * AP2 * 2];  // 6.75 KB: AmatT, aliased g_s/o1_s
    _Float16 (*AmatT)[AP2] = (_Float16 (*)[AP2])r3;
    float* g_s  = (float*)r3;                          // [NB][H]  (2 KB)
    float* o1_s = (float*)(r3 + NB * H * 4);           // [NB][HO] (1 KB)

    const int tid  = threadIdx.x;
    const int lane = tid & 63, wave = tid >> 6;
    const int q = lane >> 4, qm = lane & 15;

    // zero tT K-pad cols [48,64) once (never overwritten; reads are barrier-ordered)
    #pragma unroll
    for (int i = 0; i < 4; ++i) {
        int idx = tid + 256 * i;                       // 128 rows x 8 dwords
        int r = idx >> 3, c = (idx & 7) * 2;
        *(unsigned*)&tT[r][48 + c] = 0u;
    }

    // ---- prefetch group 0 (x B-frags + lon) into registers ----
    float4 pxa[3], pxb[3];
    float  plon;
    {
        const float* xg = x + (size_t)blockIdx.x * NB * (PP * DIN);
        #pragma unroll
        for (int nt = 0; nt < 3; ++nt) {
            const float* p = xg + (16 * nt + qm) * DIN + 8 * q;
            pxa[nt] = *(const float4*)p;
            pxb[nt] = *(const float4*)(p + 4);
        }
        plon = (lane < PP) ? xg[(wave * PP + lane) * DIN] : 0.f;
    }

    #pragma unroll 1
    for (int g = 0; g < ngroups; ++g) {
        const size_t gbase = ((size_t)g * GRID + blockIdx.x) * NB;

        // consume prefetched values; immediately issue next group's loads
        float4 cxa[3], cxb[3];
        float lon_own = plon;
        #pragma unroll
        for (int nt = 0; nt < 3; ++nt) { cxa[nt] = pxa[nt]; cxb[nt] = pxb[nt]; }
        if (g + 1 < ngroups) {
            const float* xn = x + ((size_t)(g + 1) * GRID + blockIdx.x) * NB * (PP * DIN);
            #pragma unroll
            for (int nt = 0; nt < 3; ++nt) {
                const float* p = xn + (16 * nt + qm) * DIN + 8 * q;
                pxa[nt] = *(const float4*)p;
                pxb[nt] = *(const float4*)(p + 4);
            }
            plon = (lane < PP) ? xn[(wave * PP + lane) * DIN] : 0.f;
        }

        __syncthreads();   // B0: AmatT region clear of previous head g_s/o1_s reads

        // ---- adjacency via shfl (bit-exact fp32 mask); wave w = batch w of group ----
        {
            float lonj[PP];
            #pragma unroll
            for (int j = 0; j < PP; ++j) lonj[j] = __shfl(lon_own, j, 64);
            float deg = 1.0f;                           // GCNConv's appended self-loop
            #pragma unroll
            for (int j = 0; j < PP; ++j) {
                float d = fabsf(lon_own - lonj[j]);
                d = fminf(d, 360.0f - d);
                deg += (d < 10.0f) ? 1.0f : 0.0f;       // diag: d=0 -> 1
            }
            float dinv_own = rsqrtf(fmaxf(deg, 1e-12f));
            float dj[PP];
            #pragma unroll
            for (int j = 0; j < PP; ++j) dj[j] = __shfl(dinv_own, j, 64);

            if (lane < PP) {
                const int n = wave * PP + lane;
                half8v z = {0, 0, 0, 0, 0, 0, 0, 0};
                #pragma unroll
                for (int c = 0; c < 64; c += 8) *(half8v*)&AmatT[n][c] = z;
                _Float16 vals[PP];
                #pragma unroll
                for (int j = 0; j < PP; ++j) {
                    float d = fabsf(lon_own - lonj[j]);
                    d = fminf(d, 360.0f - d);
                    float a = (d < 10.0f) ? 1.0f : 0.0f;
                    if (j == lane) a += 1.0f;           // A = mask + eye: diag = 2
                    vals[j] = (_Float16)(a * dinv_own * dj[j]);
                }
                #pragma unroll
                for (int t4 = 0; t4 < 3; ++t4) {
                    half4v v;
                    v[0] = vals[4 * t4]; v[1] = vals[4 * t4 + 1];
                    v[2] = vals[4 * t4 + 2]; v[3] = vals[4 * t4 + 3];
                    *(half4v*)&AmatT[n][wave * PP + 4 * t4] = v;
                }
            }
        }

        // ---- proj: h0^T = WinT @ x^T -> h_a[planet][wave-own cols] ----
        {
            half8v bx[3];
            #pragma unroll
            for (int nt = 0; nt < 3; ++nt) {
                half8v h;
                h[0] = (_Float16)cxa[nt].x; h[1] = (_Float16)cxa[nt].y;
                h[2] = (_Float16)cxa[nt].z; h[3] = (_Float16)cxa[nt].w;
                h[4] = (_Float16)cxb[nt].x; h[5] = (_Float16)cxb[nt].y;
                h[6] = (_Float16)cxb[nt].z; h[7] = (_Float16)cxb[nt].w;
                bx[nt] = h;
            }
            #pragma unroll
            for (int mt2 = 0; mt2 < 2; ++mt2) {
                const int m = 32 * wave + 16 * mt2;
                half8v aw = *(const half8v*)&ws[(m + qm) * DIN + 8 * q];
                float4 bi = *(const float4*)&b_in[m + 4 * q];
                #pragma unroll
                for (int nt = 0; nt < 3; ++nt) {
                    float4v c = {0.f, 0.f, 0.f, 0.f};
                    c = __builtin_amdgcn_mfma_f32_16x16x32_f16(aw, bx[nt], c, 0, 0, 0);
                    half4v hv;
                    hv[0] = (_Float16)(c[0] + bi.x); hv[1] = (_Float16)(c[1] + bi.y);
                    hv[2] = (_Float16)(c[2] + bi.z); hv[3] = (_Float16)(c[3] + bi.w);
                    *(half4v*)&h_a[16 * nt + qm][m + 4 * q] = hv;
                }
            }
        }
        __syncthreads();   // B1: h_a + AmatT complete

        // Amat B-frags to VGPRs (AmatT region then dead until aliased g_s)
        half8v amf[2][3];
        #pragma unroll
        for (int kt = 0; kt < 2; ++kt)
            #pragma unroll
            for (int nt = 0; nt < 3; ++nt)
                amf[kt][nt] = *(const half8v*)&AmatT[16 * nt + qm][32 * kt + 8 * q];

        const _Float16* WgT = ws + WS_WG;
        half8v bw[2][4];
        #pragma unroll
        for (int n2 = 0; n2 < 2; ++n2)
            #pragma unroll
            for (int kt = 0; kt < 4; ++kt)
                bw[n2][kt] = *(const half8v*)&WgT[(32 * wave + 16 * n2 + qm) * H + 32 * kt + 8 * q];

        // ---- GCN layers ----
        #pragma unroll
        for (int l = 0; l < NL; ++l) {
            float4v c[3][2];
            #pragma unroll
            for (int mt = 0; mt < 3; ++mt) {
                c[mt][0] = (float4v){0.f, 0.f, 0.f, 0.f};
                c[mt][1] = (float4v){0.f, 0.f, 0.f, 0.f};
            }
            #pragma unroll
            for (int kt = 0; kt < 4; ++kt)
                #pragma unroll
                for (int mt = 0; mt < 3; ++mt) {
                    half8v a = *(const half8v*)&h_a[16 * mt + qm][32 * kt + 8 * q];
                    c[mt][0] = __builtin_amdgcn_mfma_f32_16x16x32_f16(a, bw[0][kt], c[mt][0], 0, 0, 0);
                    c[mt][1] = __builtin_amdgcn_mfma_f32_16x16x32_f16(a, bw[1][kt], c[mt][1], 0, 0, 0);
                }

            // t -> tT (wave-private rows; in-wave ordering only)
            #pragma unroll
            for (int mt = 0; mt < 3; ++mt)
                #pragma unroll
                for (int n2 = 0; n2 < 2; ++n2) {
                    half4v hv;
                    hv[0] = (_Float16)c[mt][n2][0]; hv[1] = (_Float16)c[mt][n2][1];
                    hv[2] = (_Float16)c[mt][n2][2]; hv[3] = (_Float16)c[mt][n2][3];
                    *(half4v*)&tT[32 * wave + 16 * n2 + qm][16 * mt + 4 * q] = hv;
                }

            if (l + 1 < NL) {   // prefetch next layer's W frags
                const _Float16* Wn = WgT + (l + 1) * (H * H);
                #pragma unroll
                for (int n2 = 0; n2 < 2; ++n2)
                    #pragma unroll
                    for (int kt = 0; kt < 4; ++kt)
                        bw[n2][kt] = *(const half8v*)&Wn[(32 * wave + 16 * n2 + qm) * H + 32 * kt + 8 * q];
            }
            __syncthreads();   // B2: all waves done reading h_a (WAR vs mix writes)

            half8v ak[2][2];
            #pragma unroll
            for (int mt2 = 0; mt2 < 2; ++mt2)
                #pragma unroll
                for (int kt = 0; kt < 2; ++kt)
                    ak[mt2][kt] = *(const half8v*)&tT[32 * wave + 16 * mt2 + qm][32 * kt + 8 * q];

            #pragma unroll
            for (int mt2 = 0; mt2 < 2; ++mt2) {
                float4 bg = *(const float4*)&b_gcn[l * H + 32 * wave + 16 * mt2 + 4 * q];
                #pragma unroll
                for (int nt = 0; nt < 3; ++nt) {
                    float4v d = {0.f, 0.f, 0.f, 0.f};
                    d = __builtin_amdgcn_mfma_f32_16x16x32_f16(ak[mt2][0], amf[0][nt], d, 0, 0, 0);
                    d = __builtin_amdgcn_mfma_f32_16x16x32_f16(ak[mt2][1], amf[1][nt], d, 0, 0, 0);
                    half4v hv;
                    hv[0] = (_Float16)fmaxf(d[0] + bg.x, 0.f);
                    hv[1] = (_Float16)fmaxf(d[1] + bg.y, 0.f);
                    hv[2] = (_Float16)fmaxf(d[2] + bg.z, 0.f);
                    hv[3] = (_Float16)fmaxf(d[3] + bg.w, 0.f);
                    *(half4v*)&h_a[16 * nt + qm][32 * wave + 16 * mt2 + 4 * q] = hv;
                }
            }
            if (l + 1 < NL) __syncthreads();   // B3: RAW for next layer's t reads
        }

        // ---- mean pool (wave-own cols; own-wave writes are in-order) ----
        {
            const int colw = 32 * wave + (lane & 31);
            const int bb = lane >> 5;
            #pragma unroll
            for (int s = 0; s < 2; ++s) {
                const int b = 2 * bb + s;
                float sum = 0.f;
                #pragma unroll
                for (int p = 0; p < PP; ++p) sum += (float)h_a[b * PP + p][colw];
                g_s[b * H + colw] = sum * (1.0f / 12.0f);
            }
        }
        __syncthreads();   // B4

        // ---- head1 ----
        {
            const int b4 = tid >> 6, o = tid & 63;
            float acc = b_out1[o];
            const _Float16* wr = ws + WS_W1 + o * H;
            #pragma unroll
            for (int kk = 0; kk < H / 8; ++kk) {
                half8v wv = *(const half8v*)&wr[8 * kk];
                #pragma unroll
                for (int j = 0; j < 8; ++j) acc += g_s[b4 * H + 8 * kk + j] * (float)wv[j];
            }
            o1_s[b4 * HO + o] = fmaxf(acc, 0.f);
        }
        __syncthreads();   // B5

        // ---- head2 ----
        if (tid < NB * DOUT) {
            int b = tid / DOUT, o = tid - DOUT * b;
            float acc = b_out2[o];
            #pragma unroll 8
            for (int k = 0; k < HO; ++k)
                acc += o1_s[b * HO + k] * W_out2[k * DOUT + o];
            out[(gbase + b) * DOUT + o] = acc;
        }
    }
}

extern "C" void kernel_launch(void* const* d_in, const int* in_sizes, int n_in,
                              void* d_out, int out_size, void* d_ws, size_t ws_size,
                              hipStream_t stream) {
    const float* x      = (const float*)d_in[0];
    const float* W_in   = (const float*)d_in[1];
    const float* b_in   = (const float*)d_in[2];
    const float* W_gcn  = (const float*)d_in[3];
    const float* b_gcn  = (const float*)d_in[4];
    const float* W_out1 = (const float*)d_in[5];
    const float* b_out1 = (const float*)d_in[6];
    const float* W_out2 = (const float*)d_in[7];
    const float* b_out2 = (const float*)d_in[8];
    float* outp         = (float*)d_out;
    _Float16* wsh       = (_Float16*)d_ws;

    const int B = in_sizes[0] / (PP * DIN);        // 65536
    const int ngroups = B / (GRID * NB);           // 8

    hipLaunchKernelGGL(prep_weights, dim3((WS_TOT + 255) / 256), dim3(256), 0, stream,
                       W_in, W_gcn, W_out1, wsh);
    hipLaunchKernelGGL(gnn_mfma, dim3(GRID), dim3(256), 0, stream,
                       x, b_in, b_gcn, b_out1, W_out2, b_out2, wsh, outp, ngroups);
}

// Round 6
// 1633.526 us; speedup vs baseline: 1.1255x; 1.1255x over previous
//
#include <hip/hip_runtime.h>

// GNNModel fused via fp16 MFMA 16x16x32. Adjacency bit-exact fp32.
// R6 = R5 structure with __launch_bounds__(256,3). R5's (256,4) capped the
// UNIFIED VGPR/AGPR file at 128 -> 64 arch VGPRs -> massive spills
// (WRITE_SIZE 725 MB, FETCH 2.3 GB of scratch traffic). (256,3) gives 170
// unified, which R3/R4 proved spill-free at this body complexity.
// Persistent-ish: grid 2048, 8 groups of NB=4 batches; next group's x
// prefetched into registers during current group's compute.

typedef _Float16 half8v  __attribute__((ext_vector_type(8)));
typedef _Float16 half4v  __attribute__((ext_vector_type(4)));
typedef float    float4v __attribute__((ext_vector_type(4)));

constexpr int PP = 12, DIN = 32, H = 128, HO = 64, DOUT = 3, NL = 3;
constexpr int NB = 4, ROWS = NB * PP;   // 48 rows per group
constexpr int HP  = 136;                // h_a stride (halves)
constexpr int TP  = 72;                 // tT stride; K padded 48->64
constexpr int AP2 = 72;                 // AmatT stride
constexpr int GRID = 2048;              // blocks; ngroups = B/(GRID*NB) = 8

// ws layout in halves: WinT[128][32] @0 ; WgT[3][128][128] @4096 ; W1T[64][128] @53248
constexpr int WS_WG = 4096, WS_W1 = 53248, WS_TOT = 61440;

__global__ __launch_bounds__(256)
void prep_weights(const float* __restrict__ W_in, const float* __restrict__ W_gcn,
                  const float* __restrict__ W_out1, _Float16* __restrict__ ws)
{
    int e = blockIdx.x * 256 + threadIdx.x;
    if (e < WS_WG) {                        // WinT[n][k] = W_in[k][n]
        int n = e >> 5, k = e & 31;
        ws[e] = (_Float16)W_in[k * H + n];
    } else if (e < WS_W1) {                 // WgT[l][n][k] = W_gcn[l][k][n]
        int e2 = e - WS_WG;
        int l = e2 >> 14, r = e2 & 16383, n = r >> 7, k = r & 127;
        ws[e] = (_Float16)W_gcn[l * (H * H) + k * H + n];
    } else if (e < WS_TOT) {                // W1T[o][k] = W_out1[k][o]
        int e3 = e - WS_W1;
        int o = e3 >> 7, k = e3 & 127;
        ws[e] = (_Float16)W_out1[k * HO + o];
    }
}

__global__ __launch_bounds__(256, 3)
void gnn_mfma(const float* __restrict__ x,
              const float* __restrict__ b_in,
              const float* __restrict__ b_gcn,
              const float* __restrict__ b_out1,
              const float* __restrict__ W_out2,
              const float* __restrict__ b_out2,
              const _Float16* __restrict__ ws,
              float* __restrict__ out,
              int ngroups)
{
    __shared__ _Float16 h_a[ROWS][HP];                 // 12.75 KB
    __shared__ _Float16 tT[H][TP];                     // 18 KB (wave-private rows)
    __shared__ __align__(16) char r3[ROWS * AP2 * 2];  // 6.75 KB: AmatT, aliased g_s/o1_s
    _Float16 (*AmatT)[AP2] = (_Float16 (*)[AP2])r3;
    float* g_s  = (float*)r3;                          // [NB][H]  (2 KB)
    float* o1_s = (float*)(r3 + NB * H * 4);           // [NB][HO] (1 KB)

    const int tid  = threadIdx.x;
    const int lane = tid & 63, wave = tid >> 6;
    const int q = lane >> 4, qm = lane & 15;

    // zero tT K-pad cols [48,64) once (never overwritten; reads barrier-ordered)
    #pragma unroll
    for (int i = 0; i < 4; ++i) {
        int idx = tid + 256 * i;                       // 128 rows x 8 dwords
        int r = idx >> 3, c = (idx & 7) * 2;
        *(unsigned*)&tT[r][48 + c] = 0u;
    }

    // ---- prefetch group 0 (x B-frags + lon) into registers ----
    float4 pxa[3], pxb[3];
    float  plon;
    {
        const float* xg = x + (size_t)blockIdx.x * NB * (PP * DIN);
        #pragma unroll
        for (int nt = 0; nt < 3; ++nt) {
            const float* p = xg + (16 * nt + qm) * DIN + 8 * q;
            pxa[nt] = *(const float4*)p;
            pxb[nt] = *(const float4*)(p + 4);
        }
        plon = (lane < PP) ? xg[(wave * PP + lane) * DIN] : 0.f;
    }

    #pragma unroll 1
    for (int g = 0; g < ngroups; ++g) {
        const size_t gbase = ((size_t)g * GRID + blockIdx.x) * NB;

        // consume prefetched values; immediately issue next group's loads
        float4 cxa[3], cxb[3];
        float lon_own = plon;
        #pragma unroll
        for (int nt = 0; nt < 3; ++nt) { cxa[nt] = pxa[nt]; cxb[nt] = pxb[nt]; }
        if (g + 1 < ngroups) {
            const float* xn = x + ((size_t)(g + 1) * GRID + blockIdx.x) * NB * (PP * DIN);
            #pragma unroll
            for (int nt = 0; nt < 3; ++nt) {
                const float* p = xn + (16 * nt + qm) * DIN + 8 * q;
                pxa[nt] = *(const float4*)p;
                pxb[nt] = *(const float4*)(p + 4);
            }
            plon = (lane < PP) ? xn[(wave * PP + lane) * DIN] : 0.f;
        }

        __syncthreads();   // B0: AmatT region clear of previous head g_s/o1_s reads

        // ---- adjacency via shfl (bit-exact fp32 mask); wave w = batch w of group ----
        {
            float lonj[PP];
            #pragma unroll
            for (int j = 0; j < PP; ++j) lonj[j] = __shfl(lon_own, j, 64);
            float deg = 1.0f;                           // GCNConv's appended self-loop
            #pragma unroll
            for (int j = 0; j < PP; ++j) {
                float d = fabsf(lon_own - lonj[j]);
                d = fminf(d, 360.0f - d);
                deg += (d < 10.0f) ? 1.0f : 0.0f;       // diag: d=0 -> 1
            }
            float dinv_own = rsqrtf(fmaxf(deg, 1e-12f));
            float dj[PP];
            #pragma unroll
            for (int j = 0; j < PP; ++j) dj[j] = __shfl(dinv_own, j, 64);

            if (lane < PP) {
                const int n = wave * PP + lane;
                half8v z = {0, 0, 0, 0, 0, 0, 0, 0};
                #pragma unroll
                for (int c = 0; c < 64; c += 8) *(half8v*)&AmatT[n][c] = z;
                _Float16 vals[PP];
                #pragma unroll
                for (int j = 0; j < PP; ++j) {
                    float d = fabsf(lon_own - lonj[j]);
                    d = fminf(d, 360.0f - d);
                    float a = (d < 10.0f) ? 1.0f : 0.0f;
                    if (j == lane) a += 1.0f;           // A = mask + eye: diag = 2
                    vals[j] = (_Float16)(a * dinv_own * dj[j]);
                }
                #pragma unroll
                for (int t4 = 0; t4 < 3; ++t4) {
                    half4v v;
                    v[0] = vals[4 * t4]; v[1] = vals[4 * t4 + 1];
                    v[2] = vals[4 * t4 + 2]; v[3] = vals[4 * t4 + 3];
                    *(half4v*)&AmatT[n][wave * PP + 4 * t4] = v;
                }
            }
        }

        // ---- proj: h0^T = WinT @ x^T -> h_a[planet][wave-own cols] ----
        {
            half8v bx[3];
            #pragma unroll
            for (int nt = 0; nt < 3; ++nt) {
                half8v h;
                h[0] = (_Float16)cxa[nt].x; h[1] = (_Float16)cxa[nt].y;
                h[2] = (_Float16)cxa[nt].z; h[3] = (_Float16)cxa[nt].w;
                h[4] = (_Float16)cxb[nt].x; h[5] = (_Float16)cxb[nt].y;
                h[6] = (_Float16)cxb[nt].z; h[7] = (_Float16)cxb[nt].w;
                bx[nt] = h;
            }
            #pragma unroll
            for (int mt2 = 0; mt2 < 2; ++mt2) {
                const int m = 32 * wave + 16 * mt2;
                half8v aw = *(const half8v*)&ws[(m + qm) * DIN + 8 * q];
                float4 bi = *(const float4*)&b_in[m + 4 * q];
                #pragma unroll
                for (int nt = 0; nt < 3; ++nt) {
                    float4v c = {0.f, 0.f, 0.f, 0.f};
                    c = __builtin_amdgcn_mfma_f32_16x16x32_f16(aw, bx[nt], c, 0, 0, 0);
                    half4v hv;
                    hv[0] = (_Float16)(c[0] + bi.x); hv[1] = (_Float16)(c[1] + bi.y);
                    hv[2] = (_Float16)(c[2] + bi.z); hv[3] = (_Float16)(c[3] + bi.w);
                    *(half4v*)&h_a[16 * nt + qm][m + 4 * q] = hv;
                }
            }
        }
        __syncthreads();   // B1: h_a + AmatT complete

        // Amat B-frags to VGPRs (AmatT region then dead until aliased g_s)
        half8v amf[2][3];
        #pragma unroll
        for (int kt = 0; kt < 2; ++kt)
            #pragma unroll
            for (int nt = 0; nt < 3; ++nt)
                amf[kt][nt] = *(const half8v*)&AmatT[16 * nt + qm][32 * kt + 8 * q];

        const _Float16* WgT = ws + WS_WG;
        half8v bw[2][4];
        #pragma unroll
        for (int n2 = 0; n2 < 2; ++n2)
            #pragma unroll
            for (int kt = 0; kt < 4; ++kt)
                bw[n2][kt] = *(const half8v*)&WgT[(32 * wave + 16 * n2 + qm) * H + 32 * kt + 8 * q];

        // ---- GCN layers ----
        #pragma unroll
        for (int l = 0; l < NL; ++l) {
            float4v c[3][2];
            #pragma unroll
            for (int mt = 0; mt < 3; ++mt) {
                c[mt][0] = (float4v){0.f, 0.f, 0.f, 0.f};
                c[mt][1] = (float4v){0.f, 0.f, 0.f, 0.f};
            }
            #pragma unroll
            for (int kt = 0; kt < 4; ++kt)
                #pragma unroll
                for (int mt = 0; mt < 3; ++mt) {
                    half8v a = *(const half8v*)&h_a[16 * mt + qm][32 * kt + 8 * q];
                    c[mt][0] = __builtin_amdgcn_mfma_f32_16x16x32_f16(a, bw[0][kt], c[mt][0], 0, 0, 0);
                    c[mt][1] = __builtin_amdgcn_mfma_f32_16x16x32_f16(a, bw[1][kt], c[mt][1], 0, 0, 0);
                }

            // t -> tT (wave-private rows; in-wave ordering only)
            #pragma unroll
            for (int mt = 0; mt < 3; ++mt)
                #pragma unroll
                for (int n2 = 0; n2 < 2; ++n2) {
                    half4v hv;
                    hv[0] = (_Float16)c[mt][n2][0]; hv[1] = (_Float16)c[mt][n2][1];
                    hv[2] = (_Float16)c[mt][n2][2]; hv[3] = (_Float16)c[mt][n2][3];
                    *(half4v*)&tT[32 * wave + 16 * n2 + qm][16 * mt + 4 * q] = hv;
                }

            if (l + 1 < NL) {   // prefetch next layer's W frags
                const _Float16* Wn = WgT + (l + 1) * (H * H);
                #pragma unroll
                for (int n2 = 0; n2 < 2; ++n2)
                    #pragma unroll
                    for (int kt = 0; kt < 4; ++kt)
                        bw[n2][kt] = *(const half8v*)&Wn[(32 * wave + 16 * n2 + qm) * H + 32 * kt + 8 * q];
            }
            __syncthreads();   // B2: all waves done reading h_a (WAR vs mix writes)

            half8v ak[2][2];
            #pragma unroll
            for (int mt2 = 0; mt2 < 2; ++mt2)
                #pragma unroll
                for (int kt = 0; kt < 2; ++kt)
                    ak[mt2][kt] = *(const half8v*)&tT[32 * wave + 16 * mt2 + qm][32 * kt + 8 * q];

            #pragma unroll
            for (int mt2 = 0; mt2 < 2; ++mt2) {
                float4 bg = *(const float4*)&b_gcn[l * H + 32 * wave + 16 * mt2 + 4 * q];
                #pragma unroll
                for (int nt = 0; nt < 3; ++nt) {
                    float4v d = {0.f, 0.f, 0.f, 0.f};
                    d = __builtin_amdgcn_mfma_f32_16x16x32_f16(ak[mt2][0], amf[0][nt], d, 0, 0, 0);
                    d = __builtin_amdgcn_mfma_f32_16x16x32_f16(ak[mt2][1], amf[1][nt], d, 0, 0, 0);
                    half4v hv;
                    hv[0] = (_Float16)fmaxf(d[0] + bg.x, 0.f);
                    hv[1] = (_Float16)fmaxf(d[1] + bg.y, 0.f);
                    hv[2] = (_Float16)fmaxf(d[2] + bg.z, 0.f);
                    hv[3] = (_Float16)fmaxf(d[3] + bg.w, 0.f);
                    *(half4v*)&h_a[16 * nt + qm][32 * wave + 16 * mt2 + 4 * q] = hv;
                }
            }
            if (l + 1 < NL) __syncthreads();   // B3: RAW for next layer's t reads
        }

        // ---- mean pool (wave-own cols; own-wave writes are in-order) ----
        {
            const int colw = 32 * wave + (lane & 31);
            const int bb = lane >> 5;
            #pragma unroll
            for (int s = 0; s < 2; ++s) {
                const int b = 2 * bb + s;
                float sum = 0.f;
                #pragma unroll
                for (int p = 0; p < PP; ++p) sum += (float)h_a[b * PP + p][colw];
                g_s[b * H + colw] = sum * (1.0f / 12.0f);
            }
        }
        __syncthreads();   // B4

        // ---- head1 ----
        {
            const int b4 = tid >> 6, o = tid & 63;
            float acc = b_out1[o];
            const _Float16* wr = ws + WS_W1 + o * H;
            #pragma unroll
            for (int kk = 0; kk < H / 8; ++kk) {
                half8v wv = *(const half8v*)&wr[8 * kk];
                #pragma unroll
                for (int j = 0; j < 8; ++j) acc += g_s[b4 * H + 8 * kk + j] * (float)wv[j];
            }
            o1_s[b4 * HO + o] = fmaxf(acc, 0.f);
        }
        __syncthreads();   // B5

        // ---- head2 ----
        if (tid < NB * DOUT) {
            int b = tid / DOUT, o = tid - DOUT * b;
            float acc = b_out2[o];
            #pragma unroll 8
            for (int k = 0; k < HO; ++k)
                acc += o1_s[b * HO + k] * W_out2[k * DOUT + o];
            out[(gbase + b) * DOUT + o] = acc;
        }
    }
}

extern "C" void kernel_launch(void* const* d_in, const int* in_sizes, int n_in,
                              void* d_out, int out_size, void* d_ws, size_t ws_size,
                              hipStream_t stream) {
    const float* x      = (const float*)d_in[0];
    const float* W_in   = (const float*)d_in[1];
    const float* b_in   = (const float*)d_in[2];
    const float* W_gcn  = (const float*)d_in[3];
    const float* b_gcn  = (const float*)d_in[4];
    const float* W_out1 = (const float*)d_in[5];
    const float* b_out1 = (const float*)d_in[6];
    const float* W_out2 = (const float*)d_in[7];
    const float* b_out2 = (const float*)d_in[8];
    float* outp         = (float*)d_out;
    _Float16* wsh       = (_Float16*)d_ws;

    const int B = in_sizes[0] / (PP * DIN);        // 65536
    const int ngroups = B / (GRID * NB);           // 8

    hipLaunchKernelGGL(prep_weights, dim3((WS_TOT + 255) / 256), dim3(256), 0, stream,
                       W_in, W_gcn, W_out1, wsh);
    hipLaunchKernelGGL(gnn_mfma, dim3(GRID), dim3(256), 0, stream,
                       x, b_in, b_gcn, b_out1, W_out2, b_out2, wsh, outp, ngroups);
}

// Round 7
// 486.756 us; speedup vs baseline: 3.7772x; 3.3559x over previous
//
#include <hip/hip_runtime.h>

// GNNModel fused via fp16 MFMA 16x16x32. Adjacency bit-exact fp32.
// R7: lean-register R3. Evidence: R5/R6 spilled (persistent loop + held
// frags); R2-fp32 ran 77% VALUBusy vs R3-MFMA 21% => MFMA version is
// latency-bound at 2-3 waves/SIMD. Fix = occupancy via register leanness:
// no frag is held across a barrier (bw loaded per t-phase, amf re-read from
// LDS per mix-phase, biases per layer), non-persistent grid, wave-private
// head with shfl-reduction. __launch_bounds__(256,4) targets 128 unified
// VGPRs -> 4 blocks/CU (LDS 37.5 KB also allows 4).

typedef _Float16 half8v  __attribute__((ext_vector_type(8)));
typedef _Float16 half4v  __attribute__((ext_vector_type(4)));
typedef float    float4v __attribute__((ext_vector_type(4)));

constexpr int PP = 12, DIN = 32, H = 128, HO = 64, DOUT = 3, NL = 3;
constexpr int NB = 4, ROWS = NB * PP;   // 48 rows per block
constexpr int HP  = 136;                // h_a stride (halves), 272 B
constexpr int TP  = 72;                 // tT stride (halves); K padded 48->64
constexpr int AP2 = 72;                 // AmatT stride

// ws layout in halves: WinT[128][32] @0 ; WgT[3][128][128] @4096 ; W1T[64][128] @53248
constexpr int WS_WG = 4096, WS_W1 = 53248, WS_TOT = 61440;

__global__ __launch_bounds__(256)
void prep_weights(const float* __restrict__ W_in, const float* __restrict__ W_gcn,
                  const float* __restrict__ W_out1, _Float16* __restrict__ ws)
{
    int e = blockIdx.x * 256 + threadIdx.x;
    if (e < WS_WG) {                        // WinT[n][k] = W_in[k][n]
        int n = e >> 5, k = e & 31;
        ws[e] = (_Float16)W_in[k * H + n];
    } else if (e < WS_W1) {                 // WgT[l][n][k] = W_gcn[l][k][n]
        int e2 = e - WS_WG;
        int l = e2 >> 14, r = e2 & 16383, n = r >> 7, k = r & 127;
        ws[e] = (_Float16)W_gcn[l * (H * H) + k * H + n];
    } else if (e < WS_TOT) {                // W1T[o][k] = W_out1[k][o]
        int e3 = e - WS_W1;
        int o = e3 >> 7, k = e3 & 127;
        ws[e] = (_Float16)W_out1[k * HO + o];
    }
}

__global__ __launch_bounds__(256, 4)
void gnn_mfma(const float* __restrict__ x,
              const float* __restrict__ b_in,
              const float* __restrict__ b_gcn,
              const float* __restrict__ b_out1,
              const float* __restrict__ W_out2,
              const float* __restrict__ b_out2,
              const _Float16* __restrict__ ws,
              float* __restrict__ out)
{
    __shared__ _Float16 h_a[ROWS][HP];                 // 12.75 KB
    __shared__ _Float16 tT[H][TP];                     // 18 KB (wave-private rows)
    __shared__ __align__(16) char r3[ROWS * AP2 * 2];  // 6.75 KB: AmatT, later g_s
    _Float16 (*AmatT)[AP2] = (_Float16 (*)[AP2])r3;
    float (*g_s)[H] = (float (*)[H])r3;                // [4][128] fp32 (2 KB), wave-private

    const int tid  = threadIdx.x;
    const int lane = tid & 63, wave = tid >> 6;
    const int q = lane >> 4, qm = lane & 15;
    const int b0 = blockIdx.x * NB;
    const float* xblk = x + (size_t)b0 * (PP * DIN);

    // ---- issue x loads first (lon, then B-frag quads); consumed below ----
    float lon_own = 0.f;
    if (lane < PP) lon_own = xblk[(wave * PP + lane) * DIN];
    float4 xa[3], xb[3];
    #pragma unroll
    for (int nt = 0; nt < 3; ++nt) {
        const float* p = xblk + (16 * nt + qm) * DIN + 8 * q;
        xa[nt] = *(const float4*)p;
        xb[nt] = *(const float4*)(p + 4);
    }

    // ---- zero tT K-pad cols [48,64): read at mix kt=1 tail, never rewritten ----
    #pragma unroll
    for (int i = 0; i < 4; ++i) {
        int idx = tid + 256 * i;                       // 128 rows x 8 dwords
        int r = idx >> 3, c = (idx & 7) * 2;
        *(unsigned*)&tT[r][48 + c] = 0u;
    }

    // ---- adjacency via shfl (bit-exact fp32 mask); wave w = batch w ----
    {
        float lonj[PP];
        #pragma unroll
        for (int j = 0; j < PP; ++j) lonj[j] = __shfl(lon_own, j, 64);
        float deg = 1.0f;                              // GCNConv's appended self-loop
        #pragma unroll
        for (int j = 0; j < PP; ++j) {
            float d = fabsf(lon_own - lonj[j]);
            d = fminf(d, 360.0f - d);
            deg += (d < 10.0f) ? 1.0f : 0.0f;          // diag: d=0 -> 1
        }
        float dinv_own = rsqrtf(fmaxf(deg, 1e-12f));
        float dj[PP];
        #pragma unroll
        for (int j = 0; j < PP; ++j) dj[j] = __shfl(dinv_own, j, 64);

        if (lane < PP) {
            const int n = wave * PP + lane;
            half8v z = {0, 0, 0, 0, 0, 0, 0, 0};
            #pragma unroll
            for (int c = 0; c < 64; c += 8) *(half8v*)&AmatT[n][c] = z;
            _Float16 vals[PP];
            #pragma unroll
            for (int j = 0; j < PP; ++j) {
                float d = fabsf(lon_own - lonj[j]);
                d = fminf(d, 360.0f - d);
                float a = (d < 10.0f) ? 1.0f : 0.0f;
                if (j == lane) a += 1.0f;              // A = mask + eye: diag = 2
                vals[j] = (_Float16)(a * dinv_own * dj[j]);
            }
            #pragma unroll
            for (int t4 = 0; t4 < 3; ++t4) {
                half4v v;
                v[0] = vals[4 * t4]; v[1] = vals[4 * t4 + 1];
                v[2] = vals[4 * t4 + 2]; v[3] = vals[4 * t4 + 3];
                *(half4v*)&AmatT[n][wave * PP + 4 * t4] = v;
            }
        }
    }

    // ---- proj: h0^T = WinT @ x^T -> h_a[planet][wave-own cols] ----
    {
        half8v bx[3];
        #pragma unroll
        for (int nt = 0; nt < 3; ++nt) {
            half8v h;
            h[0] = (_Float16)xa[nt].x; h[1] = (_Float16)xa[nt].y;
            h[2] = (_Float16)xa[nt].z; h[3] = (_Float16)xa[nt].w;
            h[4] = (_Float16)xb[nt].x; h[5] = (_Float16)xb[nt].y;
            h[6] = (_Float16)xb[nt].z; h[7] = (_Float16)xb[nt].w;
            bx[nt] = h;
        }
        #pragma unroll
        for (int mt2 = 0; mt2 < 2; ++mt2) {
            const int m = 32 * wave + 16 * mt2;
            half8v aw = *(const half8v*)&ws[(m + qm) * DIN + 8 * q];
            float4 bi = *(const float4*)&b_in[m + 4 * q];
            #pragma unroll
            for (int nt = 0; nt < 3; ++nt) {
                float4v c = {0.f, 0.f, 0.f, 0.f};
                c = __builtin_amdgcn_mfma_f32_16x16x32_f16(aw, bx[nt], c, 0, 0, 0);
                half4v hv;
                hv[0] = (_Float16)(c[0] + bi.x); hv[1] = (_Float16)(c[1] + bi.y);
                hv[2] = (_Float16)(c[2] + bi.z); hv[3] = (_Float16)(c[3] + bi.w);
                *(half4v*)&h_a[16 * nt + qm][m + 4 * q] = hv;
            }
        }
    }
    __syncthreads();   // B1: h_a + AmatT complete

    const _Float16* WgT = ws + WS_WG;

    // ---- GCN layers; no register lives across a barrier ----
    #pragma unroll
    for (int l = 0; l < NL; ++l) {
        // load this layer's W B-frags + biases NOW (consumed within this phase)
        const _Float16* Wl = WgT + l * (H * H);
        half8v bw[2][4];
        #pragma unroll
        for (int n2 = 0; n2 < 2; ++n2)
            #pragma unroll
            for (int kt = 0; kt < 4; ++kt)
                bw[n2][kt] = *(const half8v*)&Wl[(32 * wave + 16 * n2 + qm) * H + 32 * kt + 8 * q];
        float4 bg0 = *(const float4*)&b_gcn[l * H + 32 * wave + 4 * q];
        float4 bg1 = *(const float4*)&b_gcn[l * H + 32 * wave + 16 + 4 * q];

        // t = h @ Wl
        float4v c[3][2];
        #pragma unroll
        for (int mt = 0; mt < 3; ++mt) {
            c[mt][0] = (float4v){0.f, 0.f, 0.f, 0.f};
            c[mt][1] = (float4v){0.f, 0.f, 0.f, 0.f};
        }
        #pragma unroll
        for (int kt = 0; kt < 4; ++kt)
            #pragma unroll
            for (int mt = 0; mt < 3; ++mt) {
                half8v a = *(const half8v*)&h_a[16 * mt + qm][32 * kt + 8 * q];
                c[mt][0] = __builtin_amdgcn_mfma_f32_16x16x32_f16(a, bw[0][kt], c[mt][0], 0, 0, 0);
                c[mt][1] = __builtin_amdgcn_mfma_f32_16x16x32_f16(a, bw[1][kt], c[mt][1], 0, 0, 0);
            }

        // t -> tT (wave-private rows; in-wave ordering only)
        #pragma unroll
        for (int mt = 0; mt < 3; ++mt)
            #pragma unroll
            for (int n2 = 0; n2 < 2; ++n2) {
                half4v hv;
                hv[0] = (_Float16)c[mt][n2][0]; hv[1] = (_Float16)c[mt][n2][1];
                hv[2] = (_Float16)c[mt][n2][2]; hv[3] = (_Float16)c[mt][n2][3];
                *(half4v*)&tT[32 * wave + 16 * n2 + qm][16 * mt + 4 * q] = hv;
            }
        __syncthreads();   // B2: all waves done reading h_a (WAR vs mix writes)

        // mix: h_next^T = tT @ Amat (Ahat symmetric); amf re-read from LDS
        half8v amf[2][3];
        #pragma unroll
        for (int kt = 0; kt < 2; ++kt)
            #pragma unroll
            for (int nt = 0; nt < 3; ++nt)
                amf[kt][nt] = *(const half8v*)&AmatT[16 * nt + qm][32 * kt + 8 * q];
        half8v ak[2][2];
        #pragma unroll
        for (int mt2 = 0; mt2 < 2; ++mt2)
            #pragma unroll
            for (int kt = 0; kt < 2; ++kt)
                ak[mt2][kt] = *(const half8v*)&tT[32 * wave + 16 * mt2 + qm][32 * kt + 8 * q];

        #pragma unroll
        for (int mt2 = 0; mt2 < 2; ++mt2) {
            const float4 bg = mt2 ? bg1 : bg0;
            #pragma unroll
            for (int nt = 0; nt < 3; ++nt) {
                float4v d = {0.f, 0.f, 0.f, 0.f};
                d = __builtin_amdgcn_mfma_f32_16x16x32_f16(ak[mt2][0], amf[0][nt], d, 0, 0, 0);
                d = __builtin_amdgcn_mfma_f32_16x16x32_f16(ak[mt2][1], amf[1][nt], d, 0, 0, 0);
                half4v hv;
                hv[0] = (_Float16)fmaxf(d[0] + bg.x, 0.f);
                hv[1] = (_Float16)fmaxf(d[1] + bg.y, 0.f);
                hv[2] = (_Float16)fmaxf(d[2] + bg.z, 0.f);
                hv[3] = (_Float16)fmaxf(d[3] + bg.w, 0.f);
                *(half4v*)&h_a[16 * nt + qm][32 * wave + 16 * mt2 + 4 * q] = hv;
            }
        }
        __syncthreads();   // B3: RAW for next t-phase / pool (needs all cols)
    }

    // ---- wave-private tail: wave w owns batch w end-to-end ----
    // pool: lane sums cols {lane, lane+64} over batch w's 12 rows
    {
        float s0 = 0.f, s1 = 0.f;
        #pragma unroll
        for (int p = 0; p < PP; ++p) {
            s0 += (float)h_a[wave * PP + p][lane];
            s1 += (float)h_a[wave * PP + p][lane + 64];
        }
        g_s[wave][lane]      = s0 * (1.0f / 12.0f);    // r3 alias: AmatT dead (last
        g_s[wave][lane + 64] = s1 * (1.0f / 12.0f);    // amf read was pre-B3)
    }
    // head1: lane o computes o1[o] for batch w (g reads are wave-private LDS)
    float o1;
    {
        float acc = b_out1[lane];
        const _Float16* wr = ws + WS_W1 + lane * H;
        #pragma unroll
        for (int kk = 0; kk < H / 8; ++kk) {
            half8v wv = *(const half8v*)&wr[8 * kk];
            #pragma unroll
            for (int j = 0; j < 8; ++j) acc += g_s[wave][8 * kk + j] * (float)wv[j];
        }
        o1 = fmaxf(acc, 0.f);
    }
    // head2: lane plays k; shfl-reduce the 3 outputs across the wave
    {
        float p0 = o1 * W_out2[lane * DOUT + 0];
        float p1 = o1 * W_out2[lane * DOUT + 1];
        float p2 = o1 * W_out2[lane * DOUT + 2];
        #pragma unroll
        for (int off = 32; off > 0; off >>= 1) {
            p0 += __shfl_down(p0, off, 64);
            p1 += __shfl_down(p1, off, 64);
            p2 += __shfl_down(p2, off, 64);
        }
        if (lane == 0) {
            float* o = out + (size_t)(b0 + wave) * DOUT;
            o[0] = p0 + b_out2[0];
            o[1] = p1 + b_out2[1];
            o[2] = p2 + b_out2[2];
        }
    }
}

extern "C" void kernel_launch(void* const* d_in, const int* in_sizes, int n_in,
                              void* d_out, int out_size, void* d_ws, size_t ws_size,
                              hipStream_t stream) {
    const float* x      = (const float*)d_in[0];
    const float* W_in   = (const float*)d_in[1];
    const float* b_in   = (const float*)d_in[2];
    const float* W_gcn  = (const float*)d_in[3];
    const float* b_gcn  = (const float*)d_in[4];
    const float* W_out1 = (const float*)d_in[5];
    const float* b_out1 = (const float*)d_in[6];
    const float* W_out2 = (const float*)d_in[7];
    const float* b_out2 = (const float*)d_in[8];
    float* outp         = (float*)d_out;
    _Float16* wsh       = (_Float16*)d_ws;

    const int B = in_sizes[0] / (PP * DIN);        // 65536

    hipLaunchKernelGGL(prep_weights, dim3((WS_TOT + 255) / 256), dim3(256), 0, stream,
                       W_in, W_gcn, W_out1, wsh);
    hipLaunchKernelGGL(gnn_mfma, dim3(B / NB), dim3(256), 0, stream,
                       x, b_in, b_gcn, b_out1, W_out2, b_out2, wsh, outp);
}